// Round 3
// baseline (421.372 us; speedup 1.0000x reference)
//
#include <hip/hip_runtime.h>
#include <hip/hip_bf16.h>

typedef __bf16 bf16;
typedef __bf16 bf16x8 __attribute__((ext_vector_type(8)));
typedef __bf16 bf16x4 __attribute__((ext_vector_type(4)));
typedef float f32x4 __attribute__((ext_vector_type(4)));
typedef float f32x16 __attribute__((ext_vector_type(16)));

#define NB 4
#define SEQ 2048
#define HID 2048
#define NHEAD 8
#define HDIM 256
#define MTOT (NB*SEQ)   // 8192

#define WAIT_VM8()  asm volatile("s_waitcnt vmcnt(8)" ::: "memory")
#define WAIT_VM0()  asm volatile("s_waitcnt vmcnt(0)" ::: "memory")

__device__ __forceinline__ void gl_lds16(const void* g, void* l) {
  __builtin_amdgcn_global_load_lds(
      (const __attribute__((address_space(1))) void*)g,
      (__attribute__((address_space(3))) void*)l, 16, 0, 0);
}

__device__ __forceinline__ unsigned cvtpk_bf16(float lo, float hi) {
  unsigned r;
  asm("v_cvt_pk_bf16_f32 %0, %1, %2" : "=v"(r) : "v"(lo), "v"(hi));
  return r;
}
// swaps a's hi 32 lanes with b's lo 32 lanes:
// a' = {a.lo_lanes, b.lo_lanes}, b' = {a.hi_lanes, b.hi_lanes}
__device__ __forceinline__ void permswap32(unsigned& a, unsigned& b) {
  asm volatile("v_permlane32_swap_b32 %0, %1" : "+v"(a), "+v"(b));
}

// ---------------- elementwise cast f32 -> bf16 ----------------
__global__ void cast_x_kernel(const float* __restrict__ in, bf16* __restrict__ out) {
  size_t i = (size_t)(blockIdx.x * 256 + threadIdx.x) * 8;
  float4 v0 = *(const float4*)(in + i);
  float4 v1 = *(const float4*)(in + i + 4);
  bf16x8 o;
  o[0]=(bf16)v0.x; o[1]=(bf16)v0.y; o[2]=(bf16)v0.z; o[3]=(bf16)v0.w;
  o[4]=(bf16)v1.x; o[5]=(bf16)v1.y; o[6]=(bf16)v1.z; o[7]=(bf16)v1.w;
  *(bf16x8*)(out + i) = o;
}

// ------ tiled transpose + cast, two tensors per launch (z selects) ------
__global__ void transpose_cast2_kernel(const float* __restrict__ in0, bf16* __restrict__ out0,
                                       const float* __restrict__ in1, bf16* __restrict__ out1,
                                       int R, int C) {
  __shared__ float tile[32][33];
  const float* in = blockIdx.z ? in1 : in0;
  bf16* out = blockIdx.z ? out1 : out0;
  int bx = blockIdx.x * 32, by = blockIdx.y * 32;
  int tx = threadIdx.x, ty = threadIdx.y; // (32,8)
  #pragma unroll
  for (int k = 0; k < 4; k++)
    tile[ty + 8*k][tx] = in[(size_t)(by + ty + 8*k) * C + bx + tx];
  __syncthreads();
  #pragma unroll
  for (int k = 0; k < 4; k++)
    out[(size_t)(bx + ty + 8*k) * R + by + tx] = (bf16)tile[tx][ty + 8*k];
}

// ---------------- RoPE cos/sin table: [SEQ][128] float2 ----------------
__global__ void rope_table_kernel(float2* __restrict__ tab) {
  int i = blockIdx.x * 256 + threadIdx.x;  // SEQ*128
  int s = i >> 7, p = i & 127;
  float invf = powf(10000.0f, -(float)p * (1.0f / 128.0f));
  float ang = (float)s * invf;
  float sn, cs;
  sincosf(ang, &sn, &cs);
  tab[i] = make_float2(cs, sn);
}

// ---------------- RoPE apply in-place on bf16 [rows][HEADS*256] ----------------
template<int HEADS>
__global__ void rope_apply_kernel(bf16* __restrict__ X, const float2* __restrict__ tab) {
  int i = blockIdx.x * 256 + threadIdx.x;
  int row = i / (HEADS * 32);
  int rem = i - row * (HEADS * 32);
  int h = rem >> 5;
  int p4 = (rem & 31) * 4;
  int s = row & (SEQ - 1);
  bf16* base = X + (size_t)row * (HEADS * HDIM) + h * HDIM;
  bf16x4 lo = *(bf16x4*)(base + p4);
  bf16x4 hi = *(bf16x4*)(base + p4 + 128);
  bf16x4 nlo, nhi;
  #pragma unroll
  for (int k = 0; k < 4; k++) {
    float2 cs = tab[s * 128 + p4 + k];
    float x0 = (float)lo[k], x1 = (float)hi[k];
    nlo[k] = (bf16)(x0 * cs.x - x1 * cs.y);
    nhi[k] = (bf16)(x1 * cs.x + x0 * cs.y);
  }
  *(bf16x4*)(base + p4) = nlo;
  *(bf16x4*)(base + p4 + 128) = nhi;
}

// ---------------- 128x128 bf16 GEMM (kept for the small KV projection) ------
template<int EPI>
__global__ __launch_bounds__(256, 3)
void gemm_bt_kernel(const bf16* __restrict__ A, const bf16* __restrict__ Bt,
                    void* __restrict__ Cout, int N, int K,
                    bf16* __restrict__ Kout, bf16* __restrict__ VTout)
{
  __shared__ bf16 Abuf[128 * 32];
  __shared__ bf16 Bbuf[128 * 32];
  const int t = threadIdx.x;
  const int lane = t & 63, w = t >> 6;
  const int g = lane >> 4, c = lane & 15;
  const int wm = w >> 1, wn = w & 1;
  const int m0 = blockIdx.y * 128, n0 = blockIdx.x * 128;

  f32x4 acc[4][4];
  #pragma unroll
  for (int i = 0; i < 4; i++)
    #pragma unroll
    for (int j = 0; j < 4; j++)
      acc[i][j] = (f32x4){0.f, 0.f, 0.f, 0.f};

  for (int k0 = 0; k0 < K; k0 += 32) {
    #pragma unroll
    for (int it = 0; it < 2; ++it) {
      int row = it * 64 + (t >> 2);
      int part = (t & 3) ^ (row & 3);
      gl_lds16(A  + (size_t)(m0 + row) * K + k0 + part * 8, Abuf + (it * 256 + w * 64) * 8);
      gl_lds16(Bt + (size_t)(n0 + row) * K + k0 + part * 8, Bbuf + (it * 256 + w * 64) * 8);
    }
    __syncthreads();
    bf16x8 af[4], bfr[4];
    #pragma unroll
    for (int i = 0; i < 4; i++) {
      int row = wm * 64 + i * 16 + c;
      af[i] = *(const bf16x8*)((const char*)Abuf + row * 64 + ((g * 16) ^ ((c & 3) * 16)));
    }
    #pragma unroll
    for (int j = 0; j < 4; j++) {
      int row = wn * 64 + j * 16 + c;
      bfr[j] = *(const bf16x8*)((const char*)Bbuf + row * 64 + ((g * 16) ^ ((c & 3) * 16)));
    }
    #pragma unroll
    for (int i = 0; i < 4; i++)
      #pragma unroll
      for (int j = 0; j < 4; j++)
        acc[i][j] = __builtin_amdgcn_mfma_f32_16x16x32_bf16(af[i], bfr[j], acc[i][j], 0, 0, 0);
    __syncthreads();
  }

  #pragma unroll
  for (int i = 0; i < 4; i++) {
    #pragma unroll
    for (int j = 0; j < 4; j++) {
      #pragma unroll
      for (int rr = 0; rr < 4; rr++) {
        int m = m0 + wm * 64 + i * 16 + g * 4 + rr;
        int col = n0 + wn * 64 + j * 16 + c;
        float v = acc[i][j][rr];
        if constexpr (EPI == 0) {
          ((bf16*)Cout)[(size_t)m * N + col] = (bf16)v;
        } else if constexpr (EPI == 2) {
          ((float*)Cout)[(size_t)m * N + col] = v;
        } else {
          if (col < 256) {
            Kout[(size_t)m * 256 + col] = (bf16)v;
          } else {
            int b = m >> 11, s = m & 2047;
            VTout[((size_t)b * 256 + (col - 256)) * SEQ + s] = (bf16)v;
          }
        }
      }
    }
  }
}

// ---------------- 256x256 bf16 GEMM, BK=64, dbuf + counted vmcnt ------------
// EPI 0: bf16 C.  EPI 2: f32 C.  EPI 3: fused-RoPE bf16 C (Q projection).
template<int EPI>
__global__ __launch_bounds__(512, 2)
void gemm256_kernel(const bf16* __restrict__ A, const bf16* __restrict__ Bt,
                    void* __restrict__ Cout, int N, int K,
                    const float2* __restrict__ tab)
{
  __shared__ bf16 Albs[2][256 * 64];   // 64 KB
  __shared__ bf16 Blbs[2][256 * 64];   // 64 KB
  const int t = threadIdx.x, lane = t & 63, w = t >> 6;
  const int g = lane >> 4, c = lane & 15;
  const int wm = w >> 2, wn = w & 3;             // 2 x 4 wave grid
  const int m0 = blockIdx.y * 256, n0 = blockIdx.x * 256;

  const bf16* Ab = A + (size_t)m0 * K;
  const bf16* Bb = Bt + (size_t)n0 * K;

  auto stage = [&](const bf16* G, int k0, bf16* lds) {
    #pragma unroll
    for (int it = 0; it < 4; ++it) {
      int slot = it * 512 + t;
      int row = slot >> 3, part = (slot & 7) ^ (row & 7);
      gl_lds16(G + (size_t)row * K + k0 + part * 8, lds + (it * 512 + w * 64) * 8);
    }
  };

  f32x4 acc[8][4];
  #pragma unroll
  for (int i = 0; i < 8; i++)
    #pragma unroll
    for (int j = 0; j < 4; j++)
      acc[i][j] = (f32x4){0.f, 0.f, 0.f, 0.f};

  stage(Ab, 0, &Albs[0][0]);
  stage(Bb, 0, &Blbs[0][0]);
  __builtin_amdgcn_sched_barrier(0);

  const int NT = K >> 6;
  #pragma unroll 1
  for (int kt = 0; kt < NT; ++kt) {
    const int buf = kt & 1;
    if (kt + 1 < NT) {
      stage(Ab, (kt + 1) * 64, &Albs[buf ^ 1][0]);
      stage(Bb, (kt + 1) * 64, &Blbs[buf ^ 1][0]);
    }
    __builtin_amdgcn_sched_barrier(0);
    if (kt + 1 < NT) { WAIT_VM8(); } else { WAIT_VM0(); }
    __builtin_amdgcn_s_barrier();
    __builtin_amdgcn_sched_barrier(0);

    #pragma unroll
    for (int s2 = 0; s2 < 2; s2++) {
      bf16x8 bfr[4];
      #pragma unroll
      for (int j = 0; j < 4; j++) {
        int row = (EPI == 3) ? (wn * 16 + (j & 1) * 64 + (j >> 1) * 128 + c)
                             : (wn * 64 + j * 16 + c);
        bfr[j] = *(const bf16x8*)((const char*)&Blbs[buf][0] + row * 128 +
                                  ((s2 * 64 + g * 16) ^ ((c & 7) * 16)));
      }
      #pragma unroll
      for (int i = 0; i < 8; i++) {
        int row = wm * 128 + i * 16 + c;
        const bf16x8 af = *(const bf16x8*)((const char*)&Albs[buf][0] + row * 128 +
                                           ((s2 * 64 + g * 16) ^ ((c & 7) * 16)));
        #pragma unroll
        for (int j = 0; j < 4; j++)
          acc[i][j] = __builtin_amdgcn_mfma_f32_16x16x32_bf16(af, bfr[j], acc[i][j], 0, 0, 0);
      }
    }
    __builtin_amdgcn_s_barrier();
  }

  if constexpr (EPI == 3) {
    // fused RoPE epilogue: block covers exactly one head (N-tile 256).
    #pragma unroll
    for (int i = 0; i < 8; i++) {
      #pragma unroll
      for (int rr = 0; rr < 4; rr++) {
        int m = m0 + wm * 128 + i * 16 + g * 4 + rr;
        int s = m & (SEQ - 1);
        bf16* orow = (bf16*)Cout + (size_t)m * N + n0;
        #pragma unroll
        for (int jp = 0; jp < 2; jp++) {
          int d = wn * 16 + jp * 64 + c;       // 0..127
          float2 cs = tab[s * 128 + d];
          float vlo = acc[i][jp][rr], vhi = acc[i][jp | 2][rr];
          orow[d]       = (bf16)(vlo * cs.x - vhi * cs.y);
          orow[d + 128] = (bf16)(vhi * cs.x + vlo * cs.y);
        }
      }
    }
  } else {
    #pragma unroll
    for (int i = 0; i < 8; i++) {
      #pragma unroll
      for (int j = 0; j < 4; j++) {
        #pragma unroll
        for (int rr = 0; rr < 4; rr++) {
          int m = m0 + wm * 128 + i * 16 + g * 4 + rr;
          int col = n0 + wn * 64 + j * 16 + c;
          float v = acc[i][j][rr];
          if constexpr (EPI == 0) ((bf16*)Cout)[(size_t)m * N + col] = (bf16)v;
          else                    ((float*)Cout)[(size_t)m * N + col] = v;
        }
      }
    }
  }
}

// ---------------- flash attention v3: 32x32 MFMA, swapped QK, reg softmax ----
// 256 blocks (b,h,tile i of 256 q-rows), 8 waves x 32 q-rows. K/V dbuf 128KB.
// S^T = mfma(K, Q^T): C col = q (lane&31), rows = kv over 16 regs -> softmax
// fully in-register (static max), P -> PV B-operand via cvt_pk_bf16 +
// v_permlane32_swap (hi/lo half exchange). PV computes O^T = V^T . P^T with
// A-frags straight from the VT [d][kv] LDS tile. No Plds, half the LDS-frag
// traffic of the 16x16 version. Causal tail imbalance (tile i does 4i+4
// steps) accepted this round.
__global__ __launch_bounds__(512, 2)
void attn_kernel(const bf16* __restrict__ Q, const bf16* __restrict__ Kb,
                 const bf16* __restrict__ VT, bf16* __restrict__ O)
{
  __shared__ bf16 Klds[2][64 * 256];   // 64 KB  (rows 512B, 16B-part swizzle ^row&31)
  __shared__ bf16 Vlds[2][256 * 64];   // 64 KB  (rows 128B, 16B-part swizzle ^row&7)

  const int L = blockIdx.x + 8 * blockIdx.y;     // gridDim.x == 8
  const int xcd = L & 7, slot = L >> 3;          // 32 blocks per XCD
  const int b = xcd >> 1;                        // batch per XCD-pair (K/V L2-resident)
  const int h = ((xcd & 1) << 2) | (slot & 3);   // head 0..7
  const int ti = slot >> 2;                      // q-tile 0..7 (256 rows each)
  const int last = 4 * ti + 3;

  const int t = threadIdx.x, lane = t & 63, w = t >> 6;  // w 0..7
  const int lq = lane & 31, hi = lane >> 5;
  const int q0w = ti * 256 + w * 32;
  const int q = q0w + lq;                        // this lane's q-column

  const bf16* Kbase = Kb + (size_t)b * SEQ * HDIM;
  const bf16* Vbase = VT + (size_t)b * HDIM * SEQ;

  auto stageK = [&](int kt, int buf) {
    const int kv0 = kt * 64;
    #pragma unroll
    for (int it = 0; it < 4; ++it) {
      int slot2 = it * 512 + t;
      int krow = slot2 >> 5, kpart = (slot2 & 31) ^ (krow & 31);
      gl_lds16(Kbase + (size_t)(kv0 + krow) * HDIM + kpart * 8,
               &Klds[buf][0] + (it * 512 + w * 64) * 8);
    }
  };
  auto stageV = [&](int kt, int buf) {
    const int kv0 = kt * 64;
    #pragma unroll
    for (int it = 0; it < 4; ++it) {
      int slot2 = it * 512 + t;
      int vrow = slot2 >> 3, vpart = (slot2 & 7) ^ (vrow & 7);
      gl_lds16(Vbase + (size_t)vrow * SEQ + kv0 + vpart * 8,
               &Vlds[buf][0] + (it * 512 + w * 64) * 8);
    }
  };

  stageK(0, 0);
  stageV(0, 0);
  __builtin_amdgcn_sched_barrier(0);

  // Q fragments: B-operand for S^T mfma. lane: col q, k-slot d = ch*16 + hi*8 + j
  bf16x8 qf[16];
  {
    const bf16* qp = Q + (size_t)(b * SEQ + q) * (NHEAD * HDIM) + h * HDIM + hi * 8;
    #pragma unroll
    for (int ch = 0; ch < 16; ch++) qf[ch] = *(const bf16x8*)(qp + ch * 16);
  }
  __builtin_amdgcn_sched_barrier(0);

  f32x16 acc[8];
  #pragma unroll
  for (int dt = 0; dt < 8; dt++)
    #pragma unroll
    for (int r = 0; r < 16; r++) acc[dt][r] = 0.f;
  float acc_s = 0.f;

  const float C1 = 0.09016844f;    // (1/16) * log2(e)
  const float C2 = 11.54156036f;   // 8 * log2(e)

  #pragma unroll 1
  for (int kt = 0; kt <= last; ++kt) {
    const int kv0 = kt * 64;
    const int buf = kt & 1;

    if (kt < last) { stageK(kt + 1, buf ^ 1); stageV(kt + 1, buf ^ 1); }
    __builtin_amdgcn_sched_barrier(0);
    if (kt < last) { WAIT_VM8(); } else { WAIT_VM0(); }
    __builtin_amdgcn_s_barrier();
    __builtin_amdgcn_sched_barrier(0);

    if (kv0 <= q0w + 31) {
      const int thr = q0w + lq - kv0;   // causal: zero where kv_local > thr
      #pragma unroll
      for (int sub = 0; sub < 2; sub++) {
        // ---- QK^T (swapped): S^T[32kv x 32q] over 16 d-chunks ----
        f32x16 sc;
        #pragma unroll
        for (int r = 0; r < 16; r++) sc[r] = 0.f;
        __builtin_amdgcn_s_setprio(1);
        #pragma unroll
        for (int ch = 0; ch < 16; ch++) {
          const int row = sub * 32 + lq;
          const bf16x8 kf = *(const bf16x8*)((const char*)&Klds[buf][0] + row * 512 +
                                             (((ch * 2 + hi) ^ lq) * 16));
          sc = __builtin_amdgcn_mfma_f32_32x32x16_bf16(kf, qf[ch], sc, 0, 0, 0);
        }
        __builtin_amdgcn_s_setprio(0);

        // ---- softmax (static max), in-register ----
        float e[16];
        #pragma unroll
        for (int r = 0; r < 16; r++) {
          float ev = exp2f(__builtin_fmaf(sc[r], C1, -C2));
          const int kvl = sub * 32 + (r & 3) + 8 * (r >> 2) + 4 * hi;
          ev = (kvl > thr) ? 0.f : ev;
          e[r] = ev;
          acc_s += ev;
        }

        // ---- P -> bf16 B-frags (per 16-kv chunk) + PV ----
        #pragma unroll
        for (int kc2 = 0; kc2 < 2; kc2++) {
          unsigned wA = cvtpk_bf16(e[8 * kc2 + 0], e[8 * kc2 + 1]);
          unsigned wB = cvtpk_bf16(e[8 * kc2 + 2], e[8 * kc2 + 3]);
          unsigned wC = cvtpk_bf16(e[8 * kc2 + 4], e[8 * kc2 + 5]);
          unsigned wD = cvtpk_bf16(e[8 * kc2 + 6], e[8 * kc2 + 7]);
          permswap32(wA, wC);   // wA = kv {8hi+0,1}, wC = kv {8hi+4,5}
          permswap32(wB, wD);   // wB = kv {8hi+2,3}, wD = kv {8hi+6,7}
          union { unsigned u[4]; bf16x8 v; } pw;
          pw.u[0] = wA; pw.u[1] = wB; pw.u[2] = wC; pw.u[3] = wD;

          const int kc = sub * 2 + kc2;          // 16-kv chunk 0..3
          __builtin_amdgcn_s_setprio(1);
          #pragma unroll
          for (int dt = 0; dt < 8; dt++) {
            const int drow = dt * 32 + lq;
            const bf16x8 vf = *(const bf16x8*)((const char*)&Vlds[buf][0] + drow * 128 +
                                               (((kc * 2 + hi) ^ (drow & 7)) * 16));
            acc[dt] = __builtin_amdgcn_mfma_f32_32x32x16_bf16(vf, pw.v, acc[dt], 0, 0, 0);
          }
          __builtin_amdgcn_s_setprio(0);
        }
      }
    }

    __builtin_amdgcn_s_barrier();
  }

  // ---- epilogue: combine hi/lo half sums, normalize, write O ----
  float s2 = __shfl(acc_s, lane ^ 32, 64);
  float inv = 1.0f / (acc_s + s2);
  bf16* orow = O + (size_t)(b * SEQ + q) * (NHEAD * HDIM) + h * HDIM;
  #pragma unroll
  for (int dt = 0; dt < 8; dt++) {
    #pragma unroll
    for (int g2 = 0; g2 < 4; g2++) {
      const int d = dt * 32 + g2 * 8 + 4 * hi;
      bf16x4 o4;
      #pragma unroll
      for (int rr = 0; rr < 4; rr++) o4[rr] = (bf16)(acc[dt][g2 * 4 + rr] * inv);
      *(bf16x4*)(orow + d) = o4;
    }
  }
}

// ---------------- launch ----------------
extern "C" void kernel_launch(void* const* d_in, const int* in_sizes, int n_in,
                              void* d_out, int out_size, void* d_ws, size_t ws_size,
                              hipStream_t stream) {
  const float* hs = (const float*)d_in[0];
  const float* Wq = (const float*)d_in[1];
  const float* Wk = (const float*)d_in[2];
  const float* Wv = (const float*)d_in[3];
  const float* Wo = (const float*)d_in[4];

  char* ws = (char*)d_ws;
  bf16* Xb   = (bf16*)(ws + 0);          // [8192][2048] bf16 X; later reused as attn output O
  bf16* WqT  = (bf16*)(ws + 33554432);   // [2048][2048]
  bf16* WkT  = (bf16*)(ws + 41943040);   // [256][2048]
  bf16* WvT  = (bf16*)(ws + 42991616);   // [256][2048] contiguous after WkT
  bf16* WoT  = (bf16*)(ws + 44040192);   // [2048][2048]
  bf16* Qb   = (bf16*)(ws + 52428800);   // [8192][2048]
  bf16* Kb   = (bf16*)(ws + 85983232);   // [8192][256]
  bf16* VTb  = (bf16*)(ws + 90177536);   // [4][256][2048]
  float2* tab = (float2*)(ws + 94371840); // [2048][128]

  cast_x_kernel<<<8192, 256, 0, stream>>>(hs, Xb);
  transpose_cast2_kernel<<<dim3(64, 64, 2), dim3(32, 8), 0, stream>>>(Wq, WqT, Wo, WoT, 2048, 2048);
  transpose_cast2_kernel<<<dim3(8, 64, 2),  dim3(32, 8), 0, stream>>>(Wk, WkT, Wv, WvT, 2048, 256);
  rope_table_kernel<<<1024, 256, 0, stream>>>(tab);

  // Q = rope(X @ Wq): 256^2 pipelined GEMM with fused-RoPE epilogue
  gemm256_kernel<3><<<dim3(8, 32), 512, 0, stream>>>(Xb, WqT, (void*)Qb, 2048, 2048, tab);
  // K|V = X @ [Wk|Wv]  (small: keep 128^2 kernel; V written transposed per batch)
  gemm_bt_kernel<1><<<dim3(4, 64), 256, 0, stream>>>(Xb, WkT, nullptr, 512, 2048, Kb, VTb);

  rope_apply_kernel<1><<<1024, 256, 0, stream>>>(Kb, tab);

  // 256 blocks (b,h,tile): 32x32-MFMA flash attention
  attn_kernel<<<dim3(8, 32), 512, 0, stream>>>(Qb, Kb, VTb, Xb /* O reuses X region */);

  // out = O @ Wo  (256^2 pipelined GEMM, f32 out)
  gemm256_kernel<2><<<dim3(8, 32), 512, 0, stream>>>(Xb, WoT, d_out, 2048, 2048, nullptr);
}

// Round 4
// 324.532 us; speedup vs baseline: 1.2984x; 1.2984x over previous
//
#include <hip/hip_runtime.h>
#include <hip/hip_bf16.h>

typedef __bf16 bf16;
typedef __bf16 bf16x8 __attribute__((ext_vector_type(8)));
typedef __bf16 bf16x4 __attribute__((ext_vector_type(4)));
typedef float f32x4 __attribute__((ext_vector_type(4)));

#define NB 4
#define SEQ 2048
#define HID 2048
#define NHEAD 8
#define HDIM 256
#define MTOT (NB*SEQ)   // 8192

#define WAIT_VM8()  asm volatile("s_waitcnt vmcnt(8)" ::: "memory")
#define WAIT_VM0()  asm volatile("s_waitcnt vmcnt(0)" ::: "memory")

__device__ __forceinline__ void gl_lds16(const void* g, void* l) {
  __builtin_amdgcn_global_load_lds(
      (const __attribute__((address_space(1))) void*)g,
      (__attribute__((address_space(3))) void*)l, 16, 0, 0);
}

// ---------------- fused prologue ----------------
// One launch replaces: cast_x (8192 blocks) + transpose Wq/Wo (8192) +
// transpose Wk/Wv (1024) + rope_table (1024). All independent, all
// memory-bound; fusing removes 3 launch gaps and overlaps their tails.
__global__ __launch_bounds__(256)
void prologue_kernel(const float* __restrict__ hs, bf16* __restrict__ Xb,
                     const float* __restrict__ Wq, bf16* __restrict__ WqT,
                     const float* __restrict__ Wo, bf16* __restrict__ WoT,
                     const float* __restrict__ Wk, bf16* __restrict__ WkT,
                     const float* __restrict__ Wv, bf16* __restrict__ WvT,
                     float2* __restrict__ tab)
{
  __shared__ float tile[32][33];
  const int bid = blockIdx.x;
  const int t = threadIdx.x;

  if (bid < 8192) {
    // ---- cast X f32 -> bf16 ----
    size_t i = (size_t)(bid * 256 + t) * 8;
    float4 v0 = *(const float4*)(hs + i);
    float4 v1 = *(const float4*)(hs + i + 4);
    bf16x8 o;
    o[0]=(bf16)v0.x; o[1]=(bf16)v0.y; o[2]=(bf16)v0.z; o[3]=(bf16)v0.w;
    o[4]=(bf16)v1.x; o[5]=(bf16)v1.y; o[6]=(bf16)v1.z; o[7]=(bf16)v1.w;
    *(bf16x8*)(Xb + i) = o;
  } else if (bid < 17408) {
    // ---- tiled transpose + cast ----
    const float* in; bf16* out; int R, C, bx, by;
    if (bid < 16384) {
      int id = bid - 8192;             // 2 tensors x 64x64 tiles
      int z = id >> 12, r = id & 4095;
      in = z ? Wo : Wq; out = z ? WoT : WqT; R = 2048; C = 2048;
      bx = (r & 63) * 32; by = (r >> 6) * 32;
    } else {
      int id = bid - 16384;            // 2 tensors x 8x64 tiles
      int z = id >> 9, r = id & 511;
      in = z ? Wv : Wk; out = z ? WvT : WkT; R = 2048; C = 256;
      bx = (r & 7) * 32; by = (r >> 3) * 32;
    }
    int tx = t & 31, ty = t >> 5;      // reproduces the (32,8) mapping
    #pragma unroll
    for (int k = 0; k < 4; k++)
      tile[ty + 8*k][tx] = in[(size_t)(by + ty + 8*k) * C + bx + tx];
    __syncthreads();
    #pragma unroll
    for (int k = 0; k < 4; k++)
      out[(size_t)(bx + ty + 8*k) * R + by + tx] = (bf16)tile[tx][ty + 8*k];
  } else {
    // ---- RoPE cos/sin table [SEQ][128] ----
    int i = (bid - 17408) * 256 + t;
    int s = i >> 7, p = i & 127;
    float invf = powf(10000.0f, -(float)p * (1.0f / 128.0f));
    float ang = (float)s * invf;
    float sn, cs;
    sincosf(ang, &sn, &cs);
    tab[i] = make_float2(cs, sn);
  }
}

// ---------------- RoPE apply in-place on bf16 [rows][HEADS*256] ----------------
template<int HEADS>
__global__ void rope_apply_kernel(bf16* __restrict__ X, const float2* __restrict__ tab) {
  int i = blockIdx.x * 256 + threadIdx.x;
  int row = i / (HEADS * 32);
  int rem = i - row * (HEADS * 32);
  int h = rem >> 5;
  int p4 = (rem & 31) * 4;
  int s = row & (SEQ - 1);
  bf16* base = X + (size_t)row * (HEADS * HDIM) + h * HDIM;
  bf16x4 lo = *(bf16x4*)(base + p4);
  bf16x4 hi = *(bf16x4*)(base + p4 + 128);
  bf16x4 nlo, nhi;
  #pragma unroll
  for (int k = 0; k < 4; k++) {
    float2 cs = tab[s * 128 + p4 + k];
    float x0 = (float)lo[k], x1 = (float)hi[k];
    nlo[k] = (bf16)(x0 * cs.x - x1 * cs.y);
    nhi[k] = (bf16)(x1 * cs.x + x0 * cs.y);
  }
  *(bf16x4*)(base + p4) = nlo;
  *(bf16x4*)(base + p4 + 128) = nhi;
}

// ---------------- 128x128 bf16 GEMM (kept for the small KV projection) ------
template<int EPI>
__global__ __launch_bounds__(256, 3)
void gemm_bt_kernel(const bf16* __restrict__ A, const bf16* __restrict__ Bt,
                    void* __restrict__ Cout, int N, int K,
                    bf16* __restrict__ Kout, bf16* __restrict__ VTout)
{
  __shared__ bf16 Abuf[128 * 32];
  __shared__ bf16 Bbuf[128 * 32];
  const int t = threadIdx.x;
  const int lane = t & 63, w = t >> 6;
  const int g = lane >> 4, c = lane & 15;
  const int wm = w >> 1, wn = w & 1;
  const int m0 = blockIdx.y * 128, n0 = blockIdx.x * 128;

  f32x4 acc[4][4];
  #pragma unroll
  for (int i = 0; i < 4; i++)
    #pragma unroll
    for (int j = 0; j < 4; j++)
      acc[i][j] = (f32x4){0.f, 0.f, 0.f, 0.f};

  for (int k0 = 0; k0 < K; k0 += 32) {
    #pragma unroll
    for (int it = 0; it < 2; ++it) {
      int row = it * 64 + (t >> 2);
      int part = (t & 3) ^ (row & 3);
      gl_lds16(A  + (size_t)(m0 + row) * K + k0 + part * 8, Abuf + (it * 256 + w * 64) * 8);
      gl_lds16(Bt + (size_t)(n0 + row) * K + k0 + part * 8, Bbuf + (it * 256 + w * 64) * 8);
    }
    __syncthreads();
    bf16x8 af[4], bfr[4];
    #pragma unroll
    for (int i = 0; i < 4; i++) {
      int row = wm * 64 + i * 16 + c;
      af[i] = *(const bf16x8*)((const char*)Abuf + row * 64 + ((g * 16) ^ ((c & 3) * 16)));
    }
    #pragma unroll
    for (int j = 0; j < 4; j++) {
      int row = wn * 64 + j * 16 + c;
      bfr[j] = *(const bf16x8*)((const char*)Bbuf + row * 64 + ((g * 16) ^ ((c & 3) * 16)));
    }
    #pragma unroll
    for (int i = 0; i < 4; i++)
      #pragma unroll
      for (int j = 0; j < 4; j++)
        acc[i][j] = __builtin_amdgcn_mfma_f32_16x16x32_bf16(af[i], bfr[j], acc[i][j], 0, 0, 0);
    __syncthreads();
  }

  #pragma unroll
  for (int i = 0; i < 4; i++) {
    #pragma unroll
    for (int j = 0; j < 4; j++) {
      #pragma unroll
      for (int rr = 0; rr < 4; rr++) {
        int m = m0 + wm * 64 + i * 16 + g * 4 + rr;
        int col = n0 + wn * 64 + j * 16 + c;
        float v = acc[i][j][rr];
        if constexpr (EPI == 0) {
          ((bf16*)Cout)[(size_t)m * N + col] = (bf16)v;
        } else if constexpr (EPI == 2) {
          ((float*)Cout)[(size_t)m * N + col] = v;
        } else {
          if (col < 256) {
            Kout[(size_t)m * 256 + col] = (bf16)v;
          } else {
            int b = m >> 11, s = m & 2047;
            VTout[((size_t)b * 256 + (col - 256)) * SEQ + s] = (bf16)v;
          }
        }
      }
    }
  }
}

// ---------------- 256x256 bf16 GEMM, BK=64, dbuf + counted vmcnt ------------
// EPI 0: bf16 C.  EPI 2: f32 C.  EPI 3: fused-RoPE bf16 C (Q projection).
template<int EPI>
__global__ __launch_bounds__(512, 2)
void gemm256_kernel(const bf16* __restrict__ A, const bf16* __restrict__ Bt,
                    void* __restrict__ Cout, int N, int K,
                    const float2* __restrict__ tab)
{
  __shared__ bf16 Albs[2][256 * 64];   // 64 KB
  __shared__ bf16 Blbs[2][256 * 64];   // 64 KB
  const int t = threadIdx.x, lane = t & 63, w = t >> 6;
  const int g = lane >> 4, c = lane & 15;
  const int wm = w >> 2, wn = w & 3;             // 2 x 4 wave grid
  const int m0 = blockIdx.y * 256, n0 = blockIdx.x * 256;

  const bf16* Ab = A + (size_t)m0 * K;
  const bf16* Bb = Bt + (size_t)n0 * K;

  auto stage = [&](const bf16* G, int k0, bf16* lds) {
    #pragma unroll
    for (int it = 0; it < 4; ++it) {
      int slot = it * 512 + t;
      int row = slot >> 3, part = (slot & 7) ^ (row & 7);
      gl_lds16(G + (size_t)row * K + k0 + part * 8, lds + (it * 512 + w * 64) * 8);
    }
  };

  f32x4 acc[8][4];
  #pragma unroll
  for (int i = 0; i < 8; i++)
    #pragma unroll
    for (int j = 0; j < 4; j++)
      acc[i][j] = (f32x4){0.f, 0.f, 0.f, 0.f};

  stage(Ab, 0, &Albs[0][0]);
  stage(Bb, 0, &Blbs[0][0]);
  __builtin_amdgcn_sched_barrier(0);

  const int NT = K >> 6;
  #pragma unroll 1
  for (int kt = 0; kt < NT; ++kt) {
    const int buf = kt & 1;
    if (kt + 1 < NT) {
      stage(Ab, (kt + 1) * 64, &Albs[buf ^ 1][0]);
      stage(Bb, (kt + 1) * 64, &Blbs[buf ^ 1][0]);
    }
    __builtin_amdgcn_sched_barrier(0);
    if (kt + 1 < NT) { WAIT_VM8(); } else { WAIT_VM0(); }
    __builtin_amdgcn_s_barrier();
    __builtin_amdgcn_sched_barrier(0);

    #pragma unroll
    for (int s2 = 0; s2 < 2; s2++) {
      bf16x8 bfr[4];
      #pragma unroll
      for (int j = 0; j < 4; j++) {
        int row = (EPI == 3) ? (wn * 16 + (j & 1) * 64 + (j >> 1) * 128 + c)
                             : (wn * 64 + j * 16 + c);
        bfr[j] = *(const bf16x8*)((const char*)&Blbs[buf][0] + row * 128 +
                                  ((s2 * 64 + g * 16) ^ ((c & 7) * 16)));
      }
      #pragma unroll
      for (int i = 0; i < 8; i++) {
        int row = wm * 128 + i * 16 + c;
        const bf16x8 af = *(const bf16x8*)((const char*)&Albs[buf][0] + row * 128 +
                                           ((s2 * 64 + g * 16) ^ ((c & 7) * 16)));
        #pragma unroll
        for (int j = 0; j < 4; j++)
          acc[i][j] = __builtin_amdgcn_mfma_f32_16x16x32_bf16(af, bfr[j], acc[i][j], 0, 0, 0);
      }
    }
    __builtin_amdgcn_s_barrier();
  }

  if constexpr (EPI == 3) {
    // fused RoPE epilogue: block covers exactly one head (N-tile 256).
    #pragma unroll
    for (int i = 0; i < 8; i++) {
      #pragma unroll
      for (int rr = 0; rr < 4; rr++) {
        int m = m0 + wm * 128 + i * 16 + g * 4 + rr;
        int s = m & (SEQ - 1);
        bf16* orow = (bf16*)Cout + (size_t)m * N + n0;
        #pragma unroll
        for (int jp = 0; jp < 2; jp++) {
          int d = wn * 16 + jp * 64 + c;       // 0..127
          float2 cs = tab[s * 128 + d];
          float vlo = acc[i][jp][rr], vhi = acc[i][jp | 2][rr];
          orow[d]       = (bf16)(vlo * cs.x - vhi * cs.y);
          orow[d + 128] = (bf16)(vhi * cs.x + vlo * cs.y);
        }
      }
    }
  } else {
    #pragma unroll
    for (int i = 0; i < 8; i++) {
      #pragma unroll
      for (int j = 0; j < 4; j++) {
        #pragma unroll
        for (int rr = 0; rr < 4; rr++) {
          int m = m0 + wm * 128 + i * 16 + g * 4 + rr;
          int col = n0 + wn * 64 + j * 16 + c;
          float v = acc[i][j][rr];
          if constexpr (EPI == 0) ((bf16*)Cout)[(size_t)m * N + col] = (bf16)v;
          else                    ((float*)Cout)[(size_t)m * N + col] = v;
        }
      }
    }
  }
}

// ---------------- flash attention (causal, GQA kv-head 0) ----------------
// R0 kernel verbatim (best measured: 131us attn / 330.7us total). QBLK=128
// (8 waves x 16 q-rows), K/V double-buffered in LDS, counted vmcnt(8) (never
// 0 mid-loop), shuffle-free softmax (static max + MFMA ones-trick row sum),
// XCD-aware bijective remap so XCD pair (2b,2b+1) owns batch b (K/V
// L2-resident). Sequential two-pass q-tile pairing (p, 15-p) keeps every
// block at exactly 34 K-steps (R2 lesson: co-resident pairing is imbalanced;
// sequential pairing is the only balanced decomposition).
// R1/R3 lesson: state needs ~116 VGPR; launch_bounds min-waves must stay 2.
__global__ __launch_bounds__(512, 2)
void attn_kernel(const bf16* __restrict__ Q, const bf16* __restrict__ Kb,
                 const bf16* __restrict__ VT, bf16* __restrict__ O)
{
  __shared__ bf16 Klds[2][64 * 256];   // 64 KB
  __shared__ bf16 Vlds[2][256 * 64];   // 64 KB
  __shared__ bf16 Plds[8][16 * 64];    // 16 KB

  // bijective remap of the 256 blocks: L = x + 8y; xcd = L%8 (HW round-robin)
  const int L = blockIdx.x + ((int)gridDim.x) * blockIdx.y;
  const int xcd = L & 7, slot = L >> 3;          // 32 blocks per XCD
  const int b = xcd >> 1;                        // batch per XCD-pair
  const int rem = ((xcd & 1) << 5) | slot;       // 0..63 within batch
  const int h = rem >> 3;                        // head
  const int p = rem & 7;                         // q-pair index 0..7

  const int t = threadIdx.x, lane = t & 63, w = t >> 6;  // w 0..7
  const int g = lane >> 4, c = lane & 15;

  const bf16* Kbase = Kb + (size_t)b * SEQ * HDIM;
  const bf16* Vbase = VT + (size_t)b * HDIM * SEQ;

  bf16x8 ones8;
  #pragma unroll
  for (int z = 0; z < 8; z++) ones8[z] = (bf16)1.0f;

  auto stageK = [&](int kt, int buf) {
    const int kv0 = kt * 64;
    #pragma unroll
    for (int it = 0; it < 4; ++it) {
      int slot2 = it * 512 + t;
      int krow = slot2 >> 5, kpart = (slot2 & 31) ^ (krow & 7);
      gl_lds16(Kbase + (size_t)(kv0 + krow) * HDIM + kpart * 8,
               &Klds[buf][0] + (it * 512 + w * 64) * 8);
    }
  };
  auto stageV = [&](int kt, int buf) {
    const int kv0 = kt * 64;
    #pragma unroll
    for (int it = 0; it < 4; ++it) {
      int slot2 = it * 512 + t;
      int vrow = slot2 >> 3, vpart = (slot2 & 7) ^ (vrow & 7);
      gl_lds16(Vbase + (size_t)vrow * SEQ + kv0 + vpart * 8,
               &Vlds[buf][0] + (it * 512 + w * 64) * 8);
    }
  };

  #pragma unroll 1
  for (int pass = 0; pass < 2; ++pass) {
    const int qt = pass ? (15 - p) : p;
    const int q0 = qt * 128;
    const int last = 2 * qt + 1;

    bf16x8 qf[8];
    const bf16* qp = Q + (size_t)(b * SEQ + q0 + w * 16 + c) * (NHEAD * HDIM) + h * HDIM + g * 8;
    #pragma unroll
    for (int s = 0; s < 8; s++) qf[s] = *(const bf16x8*)(qp + s * 32);
    __builtin_amdgcn_sched_barrier(0);

    stageK(0, 0);
    stageV(0, 0);
    __builtin_amdgcn_sched_barrier(0);

    f32x4 acc[16];
    #pragma unroll
    for (int f = 0; f < 16; f++) acc[f] = (f32x4){0.f, 0.f, 0.f, 0.f};
    f32x4 acc_s = (f32x4){0.f, 0.f, 0.f, 0.f};

    #pragma unroll 1
    for (int kt = 0; kt <= last; ++kt) {
      const int kv0 = kt * 64;
      const int buf = kt & 1;

      if (kt < last) { stageK(kt + 1, buf ^ 1); stageV(kt + 1, buf ^ 1); }
      __builtin_amdgcn_sched_barrier(0);
      if (kt < last) { WAIT_VM8(); } else { WAIT_VM0(); }
      __builtin_amdgcn_s_barrier();
      __builtin_amdgcn_sched_barrier(0);

      const int qrow_min = q0 + w * 16;
      if (kv0 <= qrow_min + 15) {
        f32x4 sc[4];
        #pragma unroll
        for (int j = 0; j < 4; j++) sc[j] = (f32x4){0.f, 0.f, 0.f, 0.f};
        __builtin_amdgcn_s_setprio(1);
        #pragma unroll
        for (int s = 0; s < 8; s++) {
          #pragma unroll
          for (int j = 0; j < 4; j++) {
            const bf16x8 kf = *(const bf16x8*)((const char*)&Klds[buf][0] + (j * 16 + c) * 512 +
                                               ((s * 64 + g * 16) ^ ((c & 7) * 16)));
            sc[j] = __builtin_amdgcn_mfma_f32_16x16x32_bf16(qf[s], kf, sc[j], 0, 0, 0);
          }
        }
        __builtin_amdgcn_s_setprio(0);

        const float C1 = 0.09016844f;    // (1/16) * log2(e)
        const float C2 = 11.54156036f;   // 8 * log2(e)
        const bool diag = (kv0 + 63 > qrow_min);
        #pragma unroll
        for (int rr = 0; rr < 4; rr++) {
          const int row = g * 4 + rr;
          const int qrow = qrow_min + row;
          #pragma unroll
          for (int j = 0; j < 4; j++) {
            float e = exp2f(__builtin_fmaf(sc[j][rr], C1, -C2));
            if (diag && (kv0 + j * 16 + c > qrow)) e = 0.f;
            *(bf16*)((char*)&Plds[w][0] + row * 128 + (((j * 32) + c * 2) ^ ((row & 7) << 4))) = (bf16)e;
          }
        }

        #pragma unroll
        for (int s2 = 0; s2 < 2; s2++) {
          const bf16x8 pf = *(const bf16x8*)((const char*)&Plds[w][0] + c * 128 +
                                             (((s2 * 4 + g) << 4) ^ ((c & 7) << 4)));
          __builtin_amdgcn_s_setprio(1);
          #pragma unroll
          for (int f = 0; f < 16; f++) {
            const bf16x8 vf = *(const bf16x8*)((const char*)&Vlds[buf][0] + (f * 16 + c) * 128 +
                                               ((s2 * 64 + g * 16) ^ ((c & 7) * 16)));
            acc[f] = __builtin_amdgcn_mfma_f32_16x16x32_bf16(pf, vf, acc[f], 0, 0, 0);
          }
          acc_s = __builtin_amdgcn_mfma_f32_16x16x32_bf16(pf, ones8, acc_s, 0, 0, 0);
          __builtin_amdgcn_s_setprio(0);
        }
      }

      __builtin_amdgcn_s_barrier();
    }

    #pragma unroll
    for (int rr = 0; rr < 4; rr++) {
      float inv = 1.0f / acc_s[rr];
      #pragma unroll
      for (int f = 0; f < 16; f++) {
        float v = acc[f][rr] * inv;
        O[(size_t)(b * SEQ + q0 + w * 16 + g * 4 + rr) * (NHEAD * HDIM) + h * HDIM + f * 16 + c] = (bf16)v;
      }
    }
  }
}

// ---------------- launch ----------------
extern "C" void kernel_launch(void* const* d_in, const int* in_sizes, int n_in,
                              void* d_out, int out_size, void* d_ws, size_t ws_size,
                              hipStream_t stream) {
  const float* hs = (const float*)d_in[0];
  const float* Wq = (const float*)d_in[1];
  const float* Wk = (const float*)d_in[2];
  const float* Wv = (const float*)d_in[3];
  const float* Wo = (const float*)d_in[4];

  char* ws = (char*)d_ws;
  bf16* Xb   = (bf16*)(ws + 0);          // [8192][2048] bf16 X; later reused as attn output O
  bf16* WqT  = (bf16*)(ws + 33554432);   // [2048][2048]
  bf16* WkT  = (bf16*)(ws + 41943040);   // [256][2048]
  bf16* WvT  = (bf16*)(ws + 42991616);   // [256][2048] contiguous after WkT
  bf16* WoT  = (bf16*)(ws + 44040192);   // [2048][2048]
  bf16* Qb   = (bf16*)(ws + 52428800);   // [8192][2048]
  bf16* Kb   = (bf16*)(ws + 85983232);   // [8192][256]
  bf16* VTb  = (bf16*)(ws + 90177536);   // [4][256][2048]
  float2* tab = (float2*)(ws + 94371840); // [2048][128]

  // fused prologue: cast X + transpose Wq/Wo + transpose Wk/Wv + rope table
  prologue_kernel<<<18432, 256, 0, stream>>>(hs, Xb, Wq, WqT, Wo, WoT,
                                             Wk, WkT, Wv, WvT, tab);

  // Q = rope(X @ Wq): 256^2 pipelined GEMM with fused-RoPE epilogue
  gemm256_kernel<3><<<dim3(8, 32), 512, 0, stream>>>(Xb, WqT, (void*)Qb, 2048, 2048, tab);
  // K|V = X @ [Wk|Wv]  (small: keep 128^2 kernel; V written transposed per batch)
  gemm_bt_kernel<1><<<dim3(4, 64), 256, 0, stream>>>(Xb, WkT, nullptr, 512, 2048, Kb, VTb);

  rope_apply_kernel<1><<<1024, 256, 0, stream>>>(Kb, tab);

  // QBLK=128, XCD-remapped: block does q-tiles p and 15-p (34 steps each)
  attn_kernel<<<dim3(8, 32), 512, 0, stream>>>(Qb, Kb, VTb, Xb /* O reuses X region */);

  // out = O @ Wo  (256^2 pipelined GEMM, f32 out)
  gemm256_kernel<2><<<dim3(8, 32), 512, 0, stream>>>(Xb, WoT, d_out, 2048, 2048, nullptr);
}